// Round 3
// baseline (555.214 us; speedup 1.0000x reference)
//
#include <hip/hip_runtime.h>
#include <cstdint>
#include <cstddef>

// Problem constants
#define BB 2
#define HB 16
#define LL 2048
#define DD 128
#define MM 4096   // B*L
#define KK 2048   // DIM
#define N1 6144   // 3*DIM
#define N2 2048   // DIM
#define BHLD (BB*HB*LL*DD)  // 8388608 elements per q/k/v section

typedef unsigned short u16;
typedef __bf16 bf16x8 __attribute__((ext_vector_type(8)));   // 4 VGPRs: mfma 16x16x32 A/B operand
typedef short  s16x4  __attribute__((ext_vector_type(4)));   // 2 VGPRs: mfma 16x16x16 (_1k) A/B operand
typedef float  f32x4  __attribute__((ext_vector_type(4)));

typedef __attribute__((address_space(1))) void* as1_ptr;
typedef __attribute__((address_space(3))) void* as3_ptr;

// async global->LDS, 16B per lane; LDS dest = wave-uniform base + lane*16 [m97/m104]
__device__ __forceinline__ void gload16(const void* g, void* l) {
  __builtin_amdgcn_global_load_lds((as1_ptr)g, (as3_ptr)l, 16, 0, 0);
}

__device__ __forceinline__ float bf2f(u16 u) {
  union { unsigned v; float f; } c; c.v = ((unsigned)u) << 16; return c.f;
}
__device__ __forceinline__ u16 f2bf(float f) {  // round-to-nearest-even
  unsigned u = __builtin_bit_cast(unsigned, f);
  return (u16)((u + 0x7FFFu + ((u >> 16) & 1u)) >> 16);
}

// ---------------- prep kernels ----------------

__global__ __launch_bounds__(256) void f32_to_bf16_vec(
    const float* __restrict__ in, u16* __restrict__ out, int n4) {
  int i = blockIdx.x * 256 + threadIdx.x;
  if (i >= n4) return;
  float4 v = ((const float4*)in)[i];
  ushort4 o;
  o.x = f2bf(v.x); o.y = f2bf(v.y); o.z = f2bf(v.z); o.w = f2bf(v.w);
  ((ushort4*)out)[i] = o;
}

// in: fp32 [R][C] row-major  ->  out: bf16 [C][R]
__global__ __launch_bounds__(256) void transpose_f32_bf16(
    const float* __restrict__ in, u16* __restrict__ out, int R, int C) {
  __shared__ float t[32][33];
  int c0 = blockIdx.x * 32, r0 = blockIdx.y * 32;
  int tx = threadIdx.x & 31, ty = threadIdx.x >> 5;  // 8 rows per pass
#pragma unroll
  for (int i = ty; i < 32; i += 8)
    t[i][tx] = in[(size_t)(r0 + i) * C + c0 + tx];
  __syncthreads();
#pragma unroll
  for (int i = ty; i < 32; i += 8)
    out[(size_t)(c0 + i) * R + r0 + tx] = f2bf(t[tx][i]);
}

// ---------------- GEMM (A [M][K] bf16, Bt [N][K] bf16) ----------------
// m97 pattern + BK=64 + XOR chunk swizzle (719 TF on this problem at 5 blk/CU):
//   - global_load_lds width=16 staging, single-buffer, 2 barriers per 64-wide K-iter
//   - tile rows stored as 8 chunks of 8 elems; logical chunk Lc lives at physical
//     chunk Lc^(r&7). Swizzle applied on the global SOURCE address so coalescing
//     is preserved; frag reads hit all 8 bank-groups, conflict-free [m136].
//   - LDS kept at exactly 32 KB (RMS partials overlay dead As space) and VGPR
//     capped via __launch_bounds__(256,5) -> 5 blocks/CU (round-2 regression fix).
// MODE 0: epilogue FUSES bias + RMSNorm + RoPE for q,k (one 128-col block = one
//         (tensor,head) = the full D=128 reduction axis) and scatters
//         q,k as [B][H][L][D], v as [B][H][D][L] (bf16).
//         q additionally pre-scaled by (1/sqrt(D))*log2(e) so attn softmax can
//         use native v_exp_f32 (2^x) with no per-score multiply.
// MODE 1: plain fp32 row-major store [M][N] (+bias).
template<int MODE>
__global__ __launch_bounds__(256, 5) void gemm_bt(
    const u16* __restrict__ A, const u16* __restrict__ Bt,
    const float* __restrict__ bias, void* __restrict__ Cout,
    const float* __restrict__ pe, const float* __restrict__ qsc,
    const float* __restrict__ ksc,
    int Msz, int Nsz, int Ksz)
{
  __shared__ __align__(16) u16 As[128*64];   // 16 KB
  __shared__ __align__(16) u16 Bs[128*64];   // 16 KB
  const int tid  = threadIdx.x;
  const int lane = tid & 63;
  const int wid  = tid >> 6;
  const int l15  = lane & 15, quad = lane >> 4;
  const int m0 = blockIdx.y * 128, n0 = blockIdx.x * 128;
  const int wm = (wid >> 1) * 64, wn = (wid & 1) * 64;

  f32x4 acc[4][4] = {};

  for (int ks = 0; ks < Ksz; ks += 64) {
    __syncthreads();
    // staging: 1024 16B-slots per tile; slot s -> row s>>3, chunk s&7 (swizzled)
#pragma unroll
    for (int j = 0; j < 4; j++) {
      const int s = (wid*4 + j)*64 + lane;
      const int row = s >> 3, pc = (s & 7) ^ (row & 7);
      gload16(&A [(size_t)(m0 + row) * Ksz + ks + pc*8], &As[(wid*4 + j)*512]);
      gload16(&Bt[(size_t)(n0 + row) * Ksz + ks + pc*8], &Bs[(wid*4 + j)*512]);
    }
    __syncthreads();
#pragma unroll
    for (int kh = 0; kh < 2; kh++) {
      bf16x8 af[4], bfr[4];
#pragma unroll
      for (int i = 0; i < 4; i++) {
        const int r = wm + i*16 + l15;
        af[i]  = *(const bf16x8*)&As[r*64 + (((kh*4 + quad) ^ (r & 7)))*8];
      }
#pragma unroll
      for (int i = 0; i < 4; i++) {
        const int r = wn + i*16 + l15;
        bfr[i] = *(const bf16x8*)&Bs[r*64 + (((kh*4 + quad) ^ (r & 7)))*8];
      }
#pragma unroll
      for (int i = 0; i < 4; i++)
#pragma unroll
        for (int j = 0; j < 4; j++)
          acc[i][j] = __builtin_amdgcn_mfma_f32_16x16x32_bf16(af[i], bfr[j], acc[i][j], 0, 0, 0);
    }
  }

  // C/D layout: row = quad*4+reg (m), col = lane&15 (n)  [verified m89/m91]
  if (MODE == 0) {
    u16* qkvp = (u16*)Cout;
    const int t = n0 >> 11;             // whole block is one (tensor t, head hh)
    const int hh = (n0 & 2047) >> 7;
    // bias pre-add (before RMS, matching reference order; qkv_b happens to be 0)
#pragma unroll
    for (int i = 0; i < 4; i++)
#pragma unroll
      for (int j = 0; j < 4; j++) {
        const float bv = bias[n0 + wn + j*16 + l15];
#pragma unroll
        for (int r = 0; r < 4; r++) acc[i][j][r] += bv;
      }

    if (t == 2) {
      // v: plain scatter to [B][H][D][L]
#pragma unroll
      for (int i = 0; i < 4; i++)
#pragma unroll
        for (int j = 0; j < 4; j++) {
          const int d = wn + j*16 + l15;
#pragma unroll
          for (int r = 0; r < 4; r++) {
            const int row = m0 + wm + i*16 + quad*4 + r;
            const int b = row >> 11, l = row & (LL - 1);
            qkvp[(size_t)2 * BHLD + (((size_t)(b*HB + hh)) * DD + d) * LL + l] =
                f2bf(acc[i][j][r]);
          }
        }
    } else {
      // q/k: fused RMSNorm + RoPE (this block holds the full d=0..127 per row).
      // RMS cross-wave partials overlay the (now dead) As tile -> LDS stays 32 KB.
      float (*red)[2] = (float (*)[2])As;
      const float* sc = (t == 0) ? qsc : ksc;
      __syncthreads();   // all waves done reading As before overlay
      // 1) per-row sum of squares: reduce over j then over the 16 lanes l15
#pragma unroll
      for (int i = 0; i < 4; i++)
#pragma unroll
        for (int r = 0; r < 4; r++) {
          float s2 = 0.f;
#pragma unroll
          for (int j = 0; j < 4; j++) { const float v = acc[i][j][r]; s2 += v * v; }
#pragma unroll
          for (int m = 1; m < 16; m <<= 1) s2 += __shfl_xor(s2, m, 64);
          if (l15 == 0) red[wm + i*16 + quad*4 + r][wid & 1] = s2;
        }
      __syncthreads();
      // 2) normalize + scale + rotate + store
#pragma unroll
      for (int i = 0; i < 4; i++)
#pragma unroll
        for (int r = 0; r < 4; r++) {
          const int rowl = wm + i*16 + quad*4 + r;
          const float tot = red[rowl][0] + red[rowl][1];
          float rr = rsqrtf(tot * (1.0f/128.0f) + 1e-6f);
          // fold 1/sqrt(128) AND log2(e) into q: softmax becomes pure exp2
          if (t == 0) rr *= 0.08838834764831845f * 1.4426950408889634f;
          const int row = m0 + rowl, b = row >> 11, l = row & (LL - 1);
#pragma unroll
          for (int j = 0; j < 4; j++) {
            const int d = wn + j*16 + l15;
            const float y = acc[i][j][r] * rr * sc[d];
            const float p = __shfl_xor(y, 1, 64);   // pair partner (d^1), same row
            // pe layout [L][64][2][2] = (c,-s,s,c); even d uses (c,-s), odd (s,c)
            const float2 pp = *(const float2*)&pe[(size_t)l * 256 + (d >> 1) * 4 + (d & 1) * 2];
            const float o = pp.x * ((d & 1) ? p : y) + pp.y * ((d & 1) ? y : p);
            qkvp[(size_t)t * BHLD + (((size_t)(b*HB + hh)) * LL + l) * DD + d] = f2bf(o);
          }
        }
    }
  } else {
#pragma unroll
    for (int i = 0; i < 4; i++)
#pragma unroll
      for (int j = 0; j < 4; j++) {
        const int col = n0 + wn + j*16 + l15;
        const float bv = bias[col];
#pragma unroll
        for (int r = 0; r < 4; r++) {
          const int row = m0 + wm + i*16 + quad*4 + r;
          ((float*)Cout)[(size_t)row * Nsz + col] = acc[i][j][r] + bv;
        }
      }
  }
}

// ---------------- flash attention v3 ----------------
// Fixed-shift softmax: q carries (1/sqrt(D))*log2e, so score s is in log2 units
// (|s| <= sqrt(128)*log2e ~ 16.3). P = exp2(s - 12*log2e); the shift is folded
// into the MFMA C-init (accumulators start at -17.3123), softmax = bare v_exp_f32.
// Async global_load_lds double-buffered K/V tiles, 1 barrier per iter.
// LDS unpadded; bank conflicts broken by source-side XOR chunk swizzle.
// S^T = K.Q^T (16x16x32) -> P lands in A-operand layout for PV (16x16x16). O in regs.
// T5: setprio(1) around MFMA clusters (attn +4-7%, m191).
#define BKT 64
#define NSHIFT -17.312340490667562f   // -12 * log2(e)
__global__ __launch_bounds__(256, 2) void attn(
    const u16* __restrict__ qkv, u16* __restrict__ Oout)
{
  __shared__ __align__(16) u16 Ksh[2][BKT * DD];   // 2 x 16 KB
  __shared__ __align__(16) u16 Vsh[2][DD * BKT];   // 2 x 16 KB

  const int bh = blockIdx.x >> 4, qt = blockIdx.x & 15;
  const int wid = threadIdx.x >> 6, lane = threadIdx.x & 63;
  const int l15 = lane & 15, quad = lane >> 4;
  const int q0 = qt * 128 + wid * 32;
  const u16* qp = qkv + (size_t)bh * LL * DD;
  const u16* kp = qkv + (size_t)BHLD + (size_t)bh * LL * DD;
  const u16* vp = qkv + (size_t)2 * BHLD + (size_t)bh * DD * LL;  // V^T [D][L]

  // Q fragments, held for entire kernel: 2 qfrags x 4 d-frags
  bf16x8 qb[2][4];
#pragma unroll
  for (int qf = 0; qf < 2; qf++)
#pragma unroll
    for (int f = 0; f < 4; f++)
      qb[qf][f] = *(const bf16x8*)&qp[(size_t)(q0 + qf*16 + l15) * DD + f*32 + quad*8];

  float l_acc[2] = {0.f, 0.f};
  f32x4 oacc[2][8] = {};

  // async stage of one K/V tile into buffer `buf` (wave issues 4+4 instrs)
  auto stage = [&](int buf, int k0) {
#pragma unroll
    for (int j = 0; j < 4; j++) {
      const int s = (wid*4 + j)*64 + lane;
      { // K: 64 rows x 16 chunks of 16B
        const int r = s >> 4, c = s & 15;
        const int lc = (c & 8) | ((c & 7) ^ (r & 7));
        gload16(&kp[(size_t)(k0 + r) * DD + lc*8], &Ksh[buf][(wid*4 + j)*512]);
      }
      { // V^T: 128 rows x 8 chunks of 16B
        const int r = s >> 3, c = s & 7;
        const int lc = c ^ (r & 7);
        gload16(&vp[(size_t)r * LL + k0 + lc*8], &Vsh[buf][(wid*4 + j)*512]);
      }
    }
  };

  stage(0, 0);
  int cur = 0;

  for (int k0 = 0; k0 < LL; k0 += BKT) {
    __syncthreads();                       // drains buf[cur] loads; frees buf[cur^1]
    if (k0 + BKT < LL) stage(cur ^ 1, k0 + BKT);

    // S^T = K . Q^T : m = 64 keys (4 tiles), n = 16 q per qfrag
    // C-init = NSHIFT folds the softmax shift into the MFMA for free
    f32x4 s[2][4];
#pragma unroll
    for (int qf = 0; qf < 2; qf++)
#pragma unroll
      for (int mt = 0; mt < 4; mt++)
        s[qf][mt] = (f32x4){NSHIFT, NSHIFT, NSHIFT, NSHIFT};
#pragma unroll
    for (int f = 0; f < 4; f++) {
      bf16x8 kf[4];
#pragma unroll
      for (int mt = 0; mt < 4; mt++) {
        const int rr = mt*16 + l15;
        const int Lc = f*4 + quad;
        const int pc = (Lc & 8) | ((Lc & 7) ^ (rr & 7));
        kf[mt] = *(const bf16x8*)&Ksh[cur][rr*DD + pc*8];
      }
      __builtin_amdgcn_s_setprio(1);
#pragma unroll
      for (int qf = 0; qf < 2; qf++)
#pragma unroll
        for (int mt = 0; mt < 4; mt++)
          s[qf][mt] = __builtin_amdgcn_mfma_f32_16x16x32_bf16(kf[mt], qb[qf][f], s[qf][mt], 0, 0, 0);
      __builtin_amdgcn_s_setprio(0);
    }

    // P = exp2(s), accumulate l, pack P to bf16 A-frags (casts -> v_cvt_pk fusion)
    s16x4 pa[2][4];
#pragma unroll
    for (int qf = 0; qf < 2; qf++) {
#pragma unroll
      for (int mt = 0; mt < 4; mt++) {
        float p0 = __builtin_exp2f(s[qf][mt][0]);
        float p1 = __builtin_exp2f(s[qf][mt][1]);
        float p2 = __builtin_exp2f(s[qf][mt][2]);
        float p3 = __builtin_exp2f(s[qf][mt][3]);
        l_acc[qf] += (p0 + p1) + (p2 + p3);
        pa[qf][mt][0] = __builtin_bit_cast(short, (__bf16)p0);
        pa[qf][mt][1] = __builtin_bit_cast(short, (__bf16)p1);
        pa[qf][mt][2] = __builtin_bit_cast(short, (__bf16)p2);
        pa[qf][mt][3] = __builtin_bit_cast(short, (__bf16)p3);
      }
    }

    // O += P . V : per k-chunk t (16 keys), 8 d-tiles, both qfrags share vb
#pragma unroll
    for (int t = 0; t < 4; t++) {
      s16x4 vb[8];
#pragma unroll
      for (int c = 0; c < 8; c++) {
        const int rv = c*16 + l15;
        const int pc = (t*2 + (quad >> 1)) ^ (l15 & 7);
        vb[c] = *(const s16x4*)&Vsh[cur][rv*BKT + pc*8 + (quad & 1)*4];
      }
      __builtin_amdgcn_s_setprio(1);
#pragma unroll
      for (int qf = 0; qf < 2; qf++)
#pragma unroll
        for (int c = 0; c < 8; c++)
          oacc[qf][c] = __builtin_amdgcn_mfma_f32_16x16x16bf16_1k(pa[qf][t], vb[c], oacc[qf][c], 0, 0, 0);
      __builtin_amdgcn_s_setprio(0);
    }
    cur ^= 1;
  }

  // final: reduce l across the 4 quad-replicas, normalize, store
#pragma unroll
  for (int qf = 0; qf < 2; qf++) {
    l_acc[qf] += __shfl_xor(l_acc[qf], 16, 64);
    l_acc[qf] += __shfl_xor(l_acc[qf], 32, 64);
  }
  const int b = bh >> 4, h = bh & 15;
#pragma unroll
  for (int qf = 0; qf < 2; qf++) {
    float lr[4];
#pragma unroll
    for (int r = 0; r < 4; r++)
      lr[r] = 1.0f / __shfl(l_acc[qf], (quad << 4) | (quad*4 + r), 64);
#pragma unroll
    for (int c = 0; c < 8; c++)
#pragma unroll
      for (int r = 0; r < 4; r++) {
        int qrow = q0 + qf*16 + quad*4 + r;
        Oout[((size_t)(b*LL + qrow)) * N2 + h*DD + c*16 + l15] = f2bf(oacc[qf][c][r] * lr[r]);
      }
  }
}

// ---------------- launch ----------------

extern "C" void kernel_launch(void* const* d_in, const int* in_sizes, int n_in,
                              void* d_out, int out_size, void* d_ws, size_t ws_size,
                              hipStream_t stream) {
  const float* x       = (const float*)d_in[0];
  const float* pe      = (const float*)d_in[1];
  const float* qkv_w   = (const float*)d_in[2];
  const float* qkv_b   = (const float*)d_in[3];
  const float* q_scale = (const float*)d_in[4];
  const float* k_scale = (const float*)d_in[5];
  const float* proj_w  = (const float*)d_in[6];
  const float* proj_b  = (const float*)d_in[7];

  // workspace layout (bytes): needs 112 MB
  char* ws = (char*)d_ws;
  u16* xb   = (u16*)(ws + 0);           // [4096][2048] bf16   : 16 MB
  u16* w1t  = (u16*)(ws + 16777216);    // [6144][2048] bf16   : 24 MB
  u16* w2t  = (u16*)(ws + 41943040);    // [2048][2048] bf16   :  8 MB
  u16* qkv  = (u16*)(ws + 50331648);    // q,k [B,H,L,D], v [B,H,D,L] bf16 : 48 MB
  u16* attO = (u16*)(ws + 100663296);   // [4096][2048] bf16   : 16 MB

  f32_to_bf16_vec<<<(MM*KK/4)/256, 256, 0, stream>>>(x, xb, MM*KK/4);
  transpose_f32_bf16<<<dim3(N1/32, KK/32), 256, 0, stream>>>(qkv_w, w1t, KK, N1);
  transpose_f32_bf16<<<dim3(N2/32, KK/32), 256, 0, stream>>>(proj_w, w2t, KK, N2);
  gemm_bt<0><<<dim3(N1/128, MM/128), 256, 0, stream>>>(
      xb, w1t, qkv_b, (void*)qkv, pe, q_scale, k_scale, MM, N1, KK);
  attn<<<BB*HB*(LL/128), 256, 0, stream>>>(qkv, attO);
  gemm_bt<1><<<dim3(N2/128, MM/128), 256, 0, stream>>>(
      attO, w2t, proj_b, d_out, nullptr, nullptr, nullptr, MM, N2, KK);
}

// Round 4
// 428.357 us; speedup vs baseline: 1.2961x; 1.2961x over previous
//
#include <hip/hip_runtime.h>
#include <cstdint>
#include <cstddef>

// Problem constants
#define BB 2
#define HB 16
#define LL 2048
#define DD 128
#define MM 4096   // B*L
#define KK 2048   // DIM
#define N1 6144   // 3*DIM
#define N2 2048   // DIM
#define BHLD (BB*HB*LL*DD)  // 8388608 elements per q/k/v section

typedef unsigned short u16;
typedef __bf16 bf16x8 __attribute__((ext_vector_type(8)));   // 4 VGPRs: mfma 16x16x32 A/B operand
typedef short  s16x4  __attribute__((ext_vector_type(4)));   // 2 VGPRs: mfma 16x16x16 (_1k) A/B operand
typedef float  f32x4  __attribute__((ext_vector_type(4)));

typedef __attribute__((address_space(1))) void* as1_ptr;
typedef __attribute__((address_space(3))) void* as3_ptr;

// async global->LDS, 16B per lane; LDS dest = wave-uniform base + lane*16 [m97/m104]
__device__ __forceinline__ void gload16(const void* g, void* l) {
  __builtin_amdgcn_global_load_lds((as1_ptr)g, (as3_ptr)l, 16, 0, 0);
}

__device__ __forceinline__ float bf2f(u16 u) {
  union { unsigned v; float f; } c; c.v = ((unsigned)u) << 16; return c.f;
}
__device__ __forceinline__ u16 f2bf(float f) {  // round-to-nearest-even
  unsigned u = __builtin_bit_cast(unsigned, f);
  return (u16)((u + 0x7FFFu + ((u >> 16) & 1u)) >> 16);
}

// ---------------- prep kernels ----------------

__global__ __launch_bounds__(256) void f32_to_bf16_vec(
    const float* __restrict__ in, u16* __restrict__ out, int n4) {
  int i = blockIdx.x * 256 + threadIdx.x;
  if (i >= n4) return;
  float4 v = ((const float4*)in)[i];
  ushort4 o;
  o.x = f2bf(v.x); o.y = f2bf(v.y); o.z = f2bf(v.z); o.w = f2bf(v.w);
  ((ushort4*)out)[i] = o;
}

// in: fp32 [R][C] row-major  ->  out: bf16 [C][R]
__global__ __launch_bounds__(256) void transpose_f32_bf16(
    const float* __restrict__ in, u16* __restrict__ out, int R, int C) {
  __shared__ float t[32][33];
  int c0 = blockIdx.x * 32, r0 = blockIdx.y * 32;
  int tx = threadIdx.x & 31, ty = threadIdx.x >> 5;  // 8 rows per pass
#pragma unroll
  for (int i = ty; i < 32; i += 8)
    t[i][tx] = in[(size_t)(r0 + i) * C + c0 + tx];
  __syncthreads();
#pragma unroll
  for (int i = ty; i < 32; i += 8)
    out[(size_t)(c0 + i) * R + r0 + tx] = f2bf(t[tx][i]);
}

// ---------------- GEMM (A [M][K] bf16, Bt [N][K] bf16) ----------------
// m97 pattern + BK=64 + XOR chunk swizzle:
//   - global_load_lds width=16 staging, single-buffer, 2 barriers per 64-wide K-iter
//   - tile rows stored as 8 chunks of 8 elems; logical chunk Lc lives at physical
//     chunk Lc^(r&7). Swizzle applied on the global SOURCE address so coalescing
//     is preserved; frag reads hit all 8 bank-groups, conflict-free [m136].
//   - LDS kept at exactly 32 KB (RMS partials overlay dead As space).
//   - __launch_bounds__(256,4): cap 128 VGPR. NOTE (round-3 post-mortem): (256,5)
//     forces <=102 VGPR which CANNOT hold the 64-reg accumulator + epilogue temps
//     -> catastrophic scratch spill (VGPR 48, +27 MB WRITE_SIZE, 159->231 us).
//     Natural allocation is 116; 4 waves/SIMD is the true operating point.
// MODE 0: epilogue FUSES bias + RMSNorm + RoPE for q,k (one 128-col block = one
//         (tensor,head) = the full D=128 reduction axis) and scatters
//         q,k as [B][H][L][D], v as [B][H][D][L] (bf16).
//         q additionally pre-scaled by (1/sqrt(D))*log2(e) so attn softmax can
//         use native v_exp_f32 (2^x) with no per-score multiply.
// MODE 1: plain fp32 row-major store [M][N] (+bias).
template<int MODE>
__global__ __launch_bounds__(256, 4) void gemm_bt(
    const u16* __restrict__ A, const u16* __restrict__ Bt,
    const float* __restrict__ bias, void* __restrict__ Cout,
    const float* __restrict__ pe, const float* __restrict__ qsc,
    const float* __restrict__ ksc,
    int Msz, int Nsz, int Ksz)
{
  __shared__ __align__(16) u16 As[128*64];   // 16 KB
  __shared__ __align__(16) u16 Bs[128*64];   // 16 KB
  const int tid  = threadIdx.x;
  const int lane = tid & 63;
  const int wid  = tid >> 6;
  const int l15  = lane & 15, quad = lane >> 4;
  const int m0 = blockIdx.y * 128, n0 = blockIdx.x * 128;
  const int wm = (wid >> 1) * 64, wn = (wid & 1) * 64;

  f32x4 acc[4][4] = {};

  for (int ks = 0; ks < Ksz; ks += 64) {
    __syncthreads();
    // staging: 1024 16B-slots per tile; slot s -> row s>>3, chunk s&7 (swizzled)
#pragma unroll
    for (int j = 0; j < 4; j++) {
      const int s = (wid*4 + j)*64 + lane;
      const int row = s >> 3, pc = (s & 7) ^ (row & 7);
      gload16(&A [(size_t)(m0 + row) * Ksz + ks + pc*8], &As[(wid*4 + j)*512]);
      gload16(&Bt[(size_t)(n0 + row) * Ksz + ks + pc*8], &Bs[(wid*4 + j)*512]);
    }
    __syncthreads();
#pragma unroll
    for (int kh = 0; kh < 2; kh++) {
      bf16x8 af[4], bfr[4];
#pragma unroll
      for (int i = 0; i < 4; i++) {
        const int r = wm + i*16 + l15;
        af[i]  = *(const bf16x8*)&As[r*64 + (((kh*4 + quad) ^ (r & 7)))*8];
      }
#pragma unroll
      for (int i = 0; i < 4; i++) {
        const int r = wn + i*16 + l15;
        bfr[i] = *(const bf16x8*)&Bs[r*64 + (((kh*4 + quad) ^ (r & 7)))*8];
      }
#pragma unroll
      for (int i = 0; i < 4; i++)
#pragma unroll
        for (int j = 0; j < 4; j++)
          acc[i][j] = __builtin_amdgcn_mfma_f32_16x16x32_bf16(af[i], bfr[j], acc[i][j], 0, 0, 0);
    }
  }

  // C/D layout: row = quad*4+reg (m), col = lane&15 (n)  [verified m89/m91]
  if (MODE == 0) {
    u16* qkvp = (u16*)Cout;
    const int t = n0 >> 11;             // whole block is one (tensor t, head hh)
    const int hh = (n0 & 2047) >> 7;
    // bias pre-add (before RMS, matching reference order; qkv_b happens to be 0)
#pragma unroll
    for (int i = 0; i < 4; i++)
#pragma unroll
      for (int j = 0; j < 4; j++) {
        const float bv = bias[n0 + wn + j*16 + l15];
#pragma unroll
        for (int r = 0; r < 4; r++) acc[i][j][r] += bv;
      }

    if (t == 2) {
      // v: plain scatter to [B][H][D][L]
#pragma unroll
      for (int i = 0; i < 4; i++)
#pragma unroll
        for (int j = 0; j < 4; j++) {
          const int d = wn + j*16 + l15;
#pragma unroll
          for (int r = 0; r < 4; r++) {
            const int row = m0 + wm + i*16 + quad*4 + r;
            const int b = row >> 11, l = row & (LL - 1);
            qkvp[(size_t)2 * BHLD + (((size_t)(b*HB + hh)) * DD + d) * LL + l] =
                f2bf(acc[i][j][r]);
          }
        }
    } else {
      // q/k: fused RMSNorm + RoPE (this block holds the full d=0..127 per row).
      // RMS cross-wave partials overlay the (now dead) As tile -> LDS stays 32 KB.
      float (*red)[2] = (float (*)[2])As;
      const float* sc = (t == 0) ? qsc : ksc;
      __syncthreads();   // all waves done reading As before overlay
      // 1) per-row sum of squares: reduce over j then over the 16 lanes l15
#pragma unroll
      for (int i = 0; i < 4; i++)
#pragma unroll
        for (int r = 0; r < 4; r++) {
          float s2 = 0.f;
#pragma unroll
          for (int j = 0; j < 4; j++) { const float v = acc[i][j][r]; s2 += v * v; }
#pragma unroll
          for (int m = 1; m < 16; m <<= 1) s2 += __shfl_xor(s2, m, 64);
          if (l15 == 0) red[wm + i*16 + quad*4 + r][wid & 1] = s2;
        }
      __syncthreads();
      // 2) normalize + scale + rotate + store
#pragma unroll
      for (int i = 0; i < 4; i++)
#pragma unroll
        for (int r = 0; r < 4; r++) {
          const int rowl = wm + i*16 + quad*4 + r;
          const float tot = red[rowl][0] + red[rowl][1];
          float rr = rsqrtf(tot * (1.0f/128.0f) + 1e-6f);
          // fold 1/sqrt(128) AND log2(e) into q: softmax becomes pure exp2
          if (t == 0) rr *= 0.08838834764831845f * 1.4426950408889634f;
          const int row = m0 + rowl, b = row >> 11, l = row & (LL - 1);
#pragma unroll
          for (int j = 0; j < 4; j++) {
            const int d = wn + j*16 + l15;
            const float y = acc[i][j][r] * rr * sc[d];
            const float p = __shfl_xor(y, 1, 64);   // pair partner (d^1), same row
            // pe layout [L][64][2][2] = (c,-s,s,c); even d uses (c,-s), odd (s,c)
            const float2 pp = *(const float2*)&pe[(size_t)l * 256 + (d >> 1) * 4 + (d & 1) * 2];
            const float o = pp.x * ((d & 1) ? p : y) + pp.y * ((d & 1) ? y : p);
            qkvp[(size_t)t * BHLD + (((size_t)(b*HB + hh)) * LL + l) * DD + d] = f2bf(o);
          }
        }
    }
  } else {
#pragma unroll
    for (int i = 0; i < 4; i++)
#pragma unroll
      for (int j = 0; j < 4; j++) {
        const int col = n0 + wn + j*16 + l15;
        const float bv = bias[col];
#pragma unroll
        for (int r = 0; r < 4; r++) {
          const int row = m0 + wm + i*16 + quad*4 + r;
          ((float*)Cout)[(size_t)row * Nsz + col] = acc[i][j][r] + bv;
        }
      }
  }
}

// ---------------- flash attention v3 ----------------
// Fixed-shift softmax: q carries (1/sqrt(D))*log2e, so score s is in log2 units
// (|s| <= sqrt(128)*log2e ~ 16.3). P = exp2(s - 12*log2e); the shift is folded
// into the MFMA C-init (accumulators start at -17.3123), softmax = bare v_exp_f32.
// Async global_load_lds double-buffered K/V tiles, 1 barrier per iter.
// LDS unpadded; bank conflicts broken by source-side XOR chunk swizzle.
// S^T = K.Q^T (16x16x32) -> P lands in A-operand layout for PV (16x16x16). O in regs.
// T5: setprio(1) around MFMA clusters (attn +4-7%, m191).
#define BKT 64
#define NSHIFT -17.312340490667562f   // -12 * log2(e)
__global__ __launch_bounds__(256, 2) void attn(
    const u16* __restrict__ qkv, u16* __restrict__ Oout)
{
  __shared__ __align__(16) u16 Ksh[2][BKT * DD];   // 2 x 16 KB
  __shared__ __align__(16) u16 Vsh[2][DD * BKT];   // 2 x 16 KB

  const int bh = blockIdx.x >> 4, qt = blockIdx.x & 15;
  const int wid = threadIdx.x >> 6, lane = threadIdx.x & 63;
  const int l15 = lane & 15, quad = lane >> 4;
  const int q0 = qt * 128 + wid * 32;
  const u16* qp = qkv + (size_t)bh * LL * DD;
  const u16* kp = qkv + (size_t)BHLD + (size_t)bh * LL * DD;
  const u16* vp = qkv + (size_t)2 * BHLD + (size_t)bh * DD * LL;  // V^T [D][L]

  // Q fragments, held for entire kernel: 2 qfrags x 4 d-frags
  bf16x8 qb[2][4];
#pragma unroll
  for (int qf = 0; qf < 2; qf++)
#pragma unroll
    for (int f = 0; f < 4; f++)
      qb[qf][f] = *(const bf16x8*)&qp[(size_t)(q0 + qf*16 + l15) * DD + f*32 + quad*8];

  float l_acc[2] = {0.f, 0.f};
  f32x4 oacc[2][8] = {};

  // async stage of one K/V tile into buffer `buf` (wave issues 4+4 instrs)
  auto stage = [&](int buf, int k0) {
#pragma unroll
    for (int j = 0; j < 4; j++) {
      const int s = (wid*4 + j)*64 + lane;
      { // K: 64 rows x 16 chunks of 16B
        const int r = s >> 4, c = s & 15;
        const int lc = (c & 8) | ((c & 7) ^ (r & 7));
        gload16(&kp[(size_t)(k0 + r) * DD + lc*8], &Ksh[buf][(wid*4 + j)*512]);
      }
      { // V^T: 128 rows x 8 chunks of 16B
        const int r = s >> 3, c = s & 7;
        const int lc = c ^ (r & 7);
        gload16(&vp[(size_t)r * LL + k0 + lc*8], &Vsh[buf][(wid*4 + j)*512]);
      }
    }
  };

  stage(0, 0);
  int cur = 0;

  for (int k0 = 0; k0 < LL; k0 += BKT) {
    __syncthreads();                       // drains buf[cur] loads; frees buf[cur^1]
    if (k0 + BKT < LL) stage(cur ^ 1, k0 + BKT);

    // S^T = K . Q^T : m = 64 keys (4 tiles), n = 16 q per qfrag
    // C-init = NSHIFT folds the softmax shift into the MFMA for free
    f32x4 s[2][4];
#pragma unroll
    for (int qf = 0; qf < 2; qf++)
#pragma unroll
      for (int mt = 0; mt < 4; mt++)
        s[qf][mt] = (f32x4){NSHIFT, NSHIFT, NSHIFT, NSHIFT};
#pragma unroll
    for (int f = 0; f < 4; f++) {
      bf16x8 kf[4];
#pragma unroll
      for (int mt = 0; mt < 4; mt++) {
        const int rr = mt*16 + l15;
        const int Lc = f*4 + quad;
        const int pc = (Lc & 8) | ((Lc & 7) ^ (rr & 7));
        kf[mt] = *(const bf16x8*)&Ksh[cur][rr*DD + pc*8];
      }
      __builtin_amdgcn_s_setprio(1);
#pragma unroll
      for (int qf = 0; qf < 2; qf++)
#pragma unroll
        for (int mt = 0; mt < 4; mt++)
          s[qf][mt] = __builtin_amdgcn_mfma_f32_16x16x32_bf16(kf[mt], qb[qf][f], s[qf][mt], 0, 0, 0);
      __builtin_amdgcn_s_setprio(0);
    }

    // P = exp2(s), accumulate l, pack P to bf16 A-frags (casts -> v_cvt_pk fusion)
    s16x4 pa[2][4];
#pragma unroll
    for (int qf = 0; qf < 2; qf++) {
#pragma unroll
      for (int mt = 0; mt < 4; mt++) {
        float p0 = __builtin_exp2f(s[qf][mt][0]);
        float p1 = __builtin_exp2f(s[qf][mt][1]);
        float p2 = __builtin_exp2f(s[qf][mt][2]);
        float p3 = __builtin_exp2f(s[qf][mt][3]);
        l_acc[qf] += (p0 + p1) + (p2 + p3);
        pa[qf][mt][0] = __builtin_bit_cast(short, (__bf16)p0);
        pa[qf][mt][1] = __builtin_bit_cast(short, (__bf16)p1);
        pa[qf][mt][2] = __builtin_bit_cast(short, (__bf16)p2);
        pa[qf][mt][3] = __builtin_bit_cast(short, (__bf16)p3);
      }
    }

    // O += P . V : per k-chunk t (16 keys), 8 d-tiles, both qfrags share vb
#pragma unroll
    for (int t = 0; t < 4; t++) {
      s16x4 vb[8];
#pragma unroll
      for (int c = 0; c < 8; c++) {
        const int rv = c*16 + l15;
        const int pc = (t*2 + (quad >> 1)) ^ (l15 & 7);
        vb[c] = *(const s16x4*)&Vsh[cur][rv*BKT + pc*8 + (quad & 1)*4];
      }
      __builtin_amdgcn_s_setprio(1);
#pragma unroll
      for (int qf = 0; qf < 2; qf++)
#pragma unroll
        for (int c = 0; c < 8; c++)
          oacc[qf][c] = __builtin_amdgcn_mfma_f32_16x16x16bf16_1k(pa[qf][t], vb[c], oacc[qf][c], 0, 0, 0);
      __builtin_amdgcn_s_setprio(0);
    }
    cur ^= 1;
  }

  // final: reduce l across the 4 quad-replicas, normalize, store
#pragma unroll
  for (int qf = 0; qf < 2; qf++) {
    l_acc[qf] += __shfl_xor(l_acc[qf], 16, 64);
    l_acc[qf] += __shfl_xor(l_acc[qf], 32, 64);
  }
  const int b = bh >> 4, h = bh & 15;
#pragma unroll
  for (int qf = 0; qf < 2; qf++) {
    float lr[4];
#pragma unroll
    for (int r = 0; r < 4; r++)
      lr[r] = 1.0f / __shfl(l_acc[qf], (quad << 4) | (quad*4 + r), 64);
#pragma unroll
    for (int c = 0; c < 8; c++)
#pragma unroll
      for (int r = 0; r < 4; r++) {
        int qrow = q0 + qf*16 + quad*4 + r;
        Oout[((size_t)(b*LL + qrow)) * N2 + h*DD + c*16 + l15] = f2bf(oacc[qf][c][r] * lr[r]);
      }
  }
}

// ---------------- launch ----------------

extern "C" void kernel_launch(void* const* d_in, const int* in_sizes, int n_in,
                              void* d_out, int out_size, void* d_ws, size_t ws_size,
                              hipStream_t stream) {
  const float* x       = (const float*)d_in[0];
  const float* pe      = (const float*)d_in[1];
  const float* qkv_w   = (const float*)d_in[2];
  const float* qkv_b   = (const float*)d_in[3];
  const float* q_scale = (const float*)d_in[4];
  const float* k_scale = (const float*)d_in[5];
  const float* proj_w  = (const float*)d_in[6];
  const float* proj_b  = (const float*)d_in[7];

  // workspace layout (bytes): needs 112 MB
  char* ws = (char*)d_ws;
  u16* xb   = (u16*)(ws + 0);           // [4096][2048] bf16   : 16 MB
  u16* w1t  = (u16*)(ws + 16777216);    // [6144][2048] bf16   : 24 MB
  u16* w2t  = (u16*)(ws + 41943040);    // [2048][2048] bf16   :  8 MB
  u16* qkv  = (u16*)(ws + 50331648);    // q,k [B,H,L,D], v [B,H,D,L] bf16 : 48 MB
  u16* attO = (u16*)(ws + 100663296);   // [4096][2048] bf16   : 16 MB

  f32_to_bf16_vec<<<(MM*KK/4)/256, 256, 0, stream>>>(x, xb, MM*KK/4);
  transpose_f32_bf16<<<dim3(N1/32, KK/32), 256, 0, stream>>>(qkv_w, w1t, KK, N1);
  transpose_f32_bf16<<<dim3(N2/32, KK/32), 256, 0, stream>>>(proj_w, w2t, KK, N2);
  gemm_bt<0><<<dim3(N1/128, MM/128), 256, 0, stream>>>(
      xb, w1t, qkv_b, (void*)qkv, pe, q_scale, k_scale, MM, N1, KK);
  attn<<<BB*HB*(LL/128), 256, 0, stream>>>(qkv, attO);
  gemm_bt<1><<<dim3(N2/128, MM/128), 256, 0, stream>>>(
      attO, w2t, proj_b, d_out, nullptr, nullptr, nullptr, MM, N2, KK);
}

// Round 5
// 395.475 us; speedup vs baseline: 1.4039x; 1.0831x over previous
//
#include <hip/hip_runtime.h>
#include <cstdint>
#include <cstddef>

// Problem constants
#define BB 2
#define HB 16
#define LL 2048
#define DD 128
#define MM 4096   // B*L
#define KK 2048   // DIM
#define N1 6144   // 3*DIM
#define N2 2048   // DIM
#define BHLD (BB*HB*LL*DD)  // 8388608 elements per q/k/v section

typedef unsigned short u16;
typedef __bf16 bf16x8 __attribute__((ext_vector_type(8)));   // 4 VGPRs: mfma 16x16x32 A/B operand
typedef short  s16x4  __attribute__((ext_vector_type(4)));   // 2 VGPRs: mfma 16x16x16 (_1k) A/B operand
typedef float  f32x4  __attribute__((ext_vector_type(4)));

typedef __attribute__((address_space(1))) void* as1_ptr;
typedef __attribute__((address_space(3))) void* as3_ptr;

// async global->LDS, 16B per lane; LDS dest = wave-uniform base + lane*16 [m97/m104]
__device__ __forceinline__ void gload16(const void* g, void* l) {
  __builtin_amdgcn_global_load_lds((as1_ptr)g, (as3_ptr)l, 16, 0, 0);
}

__device__ __forceinline__ float bf2f(u16 u) {
  union { unsigned v; float f; } c; c.v = ((unsigned)u) << 16; return c.f;
}
__device__ __forceinline__ u16 f2bf(float f) {  // round-to-nearest-even
  unsigned u = __builtin_bit_cast(unsigned, f);
  return (u16)((u + 0x7FFFu + ((u >> 16) & 1u)) >> 16);
}

// ---------------- prep kernels ----------------

__global__ __launch_bounds__(256) void f32_to_bf16_vec(
    const float* __restrict__ in, u16* __restrict__ out, int n4) {
  int i = blockIdx.x * 256 + threadIdx.x;
  if (i >= n4) return;
  float4 v = ((const float4*)in)[i];
  ushort4 o;
  o.x = f2bf(v.x); o.y = f2bf(v.y); o.z = f2bf(v.z); o.w = f2bf(v.w);
  ((ushort4*)out)[i] = o;
}

// in: fp32 [R][C] row-major  ->  out: bf16 [C][R]
__global__ __launch_bounds__(256) void transpose_f32_bf16(
    const float* __restrict__ in, u16* __restrict__ out, int R, int C) {
  __shared__ float t[32][33];
  int c0 = blockIdx.x * 32, r0 = blockIdx.y * 32;
  int tx = threadIdx.x & 31, ty = threadIdx.x >> 5;  // 8 rows per pass
#pragma unroll
  for (int i = ty; i < 32; i += 8)
    t[i][tx] = in[(size_t)(r0 + i) * C + c0 + tx];
  __syncthreads();
#pragma unroll
  for (int i = ty; i < 32; i += 8)
    out[(size_t)(c0 + i) * R + r0 + tx] = f2bf(t[tx][i]);
}

// ---------------- GEMM (A [M][K] bf16, Bt [N][K] bf16) ----------------
// m97 pattern + BK=64 + XOR chunk swizzle:
//   - global_load_lds width=16 staging, single-buffer, 2 barriers per 64-wide K-iter
//   - tile rows stored as 8 chunks of 8 elems; logical chunk Lc lives at physical
//     chunk Lc^(r&7). Swizzle applied on the global SOURCE address so coalescing
//     is preserved; frag reads hit all 8 bank-groups, conflict-free [m136].
//   - LDS kept at exactly 32 KB (RMS partials overlay dead As space).
//   - __launch_bounds__(256,4): cap 128 VGPR -> allocator lands at 64 VGPR, no
//     spill, 126 us (round-4 measured). (256,5) forces <=102 -> catastrophic
//     spill (VGPR 48, +27 MB WRITE_SIZE, 231 us) — do not tighten.
// MODE 0: epilogue FUSES bias + RMSNorm + RoPE for q,k (one 128-col block = one
//         (tensor,head) = the full D=128 reduction axis) and scatters
//         q,k as [B][H][L][D], v as [B][H][D][L] (bf16).
//         q pre-scaled by 1/sqrt(D) so attn scores come out of MFMA ready.
// MODE 1: plain fp32 row-major store [M][N] (+bias).
template<int MODE>
__global__ __launch_bounds__(256, 4) void gemm_bt(
    const u16* __restrict__ A, const u16* __restrict__ Bt,
    const float* __restrict__ bias, void* __restrict__ Cout,
    const float* __restrict__ pe, const float* __restrict__ qsc,
    const float* __restrict__ ksc,
    int Msz, int Nsz, int Ksz)
{
  __shared__ __align__(16) u16 As[128*64];   // 16 KB
  __shared__ __align__(16) u16 Bs[128*64];   // 16 KB
  const int tid  = threadIdx.x;
  const int lane = tid & 63;
  const int wid  = tid >> 6;
  const int l15  = lane & 15, quad = lane >> 4;
  const int m0 = blockIdx.y * 128, n0 = blockIdx.x * 128;
  const int wm = (wid >> 1) * 64, wn = (wid & 1) * 64;

  f32x4 acc[4][4] = {};

  for (int ks = 0; ks < Ksz; ks += 64) {
    __syncthreads();
    // staging: 1024 16B-slots per tile; slot s -> row s>>3, chunk s&7 (swizzled)
#pragma unroll
    for (int j = 0; j < 4; j++) {
      const int s = (wid*4 + j)*64 + lane;
      const int row = s >> 3, pc = (s & 7) ^ (row & 7);
      gload16(&A [(size_t)(m0 + row) * Ksz + ks + pc*8], &As[(wid*4 + j)*512]);
      gload16(&Bt[(size_t)(n0 + row) * Ksz + ks + pc*8], &Bs[(wid*4 + j)*512]);
    }
    __syncthreads();
#pragma unroll
    for (int kh = 0; kh < 2; kh++) {
      bf16x8 af[4], bfr[4];
#pragma unroll
      for (int i = 0; i < 4; i++) {
        const int r = wm + i*16 + l15;
        af[i]  = *(const bf16x8*)&As[r*64 + (((kh*4 + quad) ^ (r & 7)))*8];
      }
#pragma unroll
      for (int i = 0; i < 4; i++) {
        const int r = wn + i*16 + l15;
        bfr[i] = *(const bf16x8*)&Bs[r*64 + (((kh*4 + quad) ^ (r & 7)))*8];
      }
#pragma unroll
      for (int i = 0; i < 4; i++)
#pragma unroll
        for (int j = 0; j < 4; j++)
          acc[i][j] = __builtin_amdgcn_mfma_f32_16x16x32_bf16(af[i], bfr[j], acc[i][j], 0, 0, 0);
    }
  }

  // C/D layout: row = quad*4+reg (m), col = lane&15 (n)  [verified m89/m91]
  if (MODE == 0) {
    u16* qkvp = (u16*)Cout;
    const int t = n0 >> 11;             // whole block is one (tensor t, head hh)
    const int hh = (n0 & 2047) >> 7;
    // bias pre-add (before RMS, matching reference order; qkv_b happens to be 0)
#pragma unroll
    for (int i = 0; i < 4; i++)
#pragma unroll
      for (int j = 0; j < 4; j++) {
        const float bv = bias[n0 + wn + j*16 + l15];
#pragma unroll
        for (int r = 0; r < 4; r++) acc[i][j][r] += bv;
      }

    if (t == 2) {
      // v: plain scatter to [B][H][D][L]
#pragma unroll
      for (int i = 0; i < 4; i++)
#pragma unroll
        for (int j = 0; j < 4; j++) {
          const int d = wn + j*16 + l15;
#pragma unroll
          for (int r = 0; r < 4; r++) {
            const int row = m0 + wm + i*16 + quad*4 + r;
            const int b = row >> 11, l = row & (LL - 1);
            qkvp[(size_t)2 * BHLD + (((size_t)(b*HB + hh)) * DD + d) * LL + l] =
                f2bf(acc[i][j][r]);
          }
        }
    } else {
      // q/k: fused RMSNorm + RoPE (this block holds the full d=0..127 per row).
      // RMS cross-wave partials overlay the (now dead) As tile -> LDS stays 32 KB.
      float (*red)[2] = (float (*)[2])As;
      const float* sc = (t == 0) ? qsc : ksc;
      __syncthreads();   // all waves done reading As before overlay
      // 1) per-row sum of squares: reduce over j then over the 16 lanes l15
#pragma unroll
      for (int i = 0; i < 4; i++)
#pragma unroll
        for (int r = 0; r < 4; r++) {
          float s2 = 0.f;
#pragma unroll
          for (int j = 0; j < 4; j++) { const float v = acc[i][j][r]; s2 += v * v; }
#pragma unroll
          for (int m = 1; m < 16; m <<= 1) s2 += __shfl_xor(s2, m, 64);
          if (l15 == 0) red[wm + i*16 + quad*4 + r][wid & 1] = s2;
        }
      __syncthreads();
      // 2) normalize + scale + rotate + store
#pragma unroll
      for (int i = 0; i < 4; i++)
#pragma unroll
        for (int r = 0; r < 4; r++) {
          const int rowl = wm + i*16 + quad*4 + r;
          const float tot = red[rowl][0] + red[rowl][1];
          float rr = rsqrtf(tot * (1.0f/128.0f) + 1e-6f);
          if (t == 0) rr *= 0.08838834764831845f;   // fold 1/sqrt(128) into q
          const int row = m0 + rowl, b = row >> 11, l = row & (LL - 1);
#pragma unroll
          for (int j = 0; j < 4; j++) {
            const int d = wn + j*16 + l15;
            const float y = acc[i][j][r] * rr * sc[d];
            const float p = __shfl_xor(y, 1, 64);   // pair partner (d^1), same row
            // pe layout [L][64][2][2] = (c,-s,s,c); even d uses (c,-s), odd (s,c)
            const float2 pp = *(const float2*)&pe[(size_t)l * 256 + (d >> 1) * 4 + (d & 1) * 2];
            const float o = pp.x * ((d & 1) ? p : y) + pp.y * ((d & 1) ? y : p);
            qkvp[(size_t)t * BHLD + (((size_t)(b*HB + hh)) * LL + l) * DD + d] = f2bf(o);
          }
        }
    }
  } else {
#pragma unroll
    for (int i = 0; i < 4; i++)
#pragma unroll
      for (int j = 0; j < 4; j++) {
        const int col = n0 + wn + j*16 + l15;
        const float bv = bias[col];
#pragma unroll
        for (int r = 0; r < 4; r++) {
          const int row = m0 + wm + i*16 + quad*4 + r;
          ((float*)Cout)[(size_t)row * Nsz + col] = acc[i][j][r] + bv;
        }
      }
  }
}

// ---------------- flash attention v3 ----------------
// Fixed-shift softmax (|s|<=sqrt(128) since q,k RMS-normed): no running max/rescale.
// (Round-5 A/B: exp2/NSHIFT variant reverted — it coincided with a ~37 us attn
//  regression in round 4; this is the exact round-2 attn that measured 424 total.)
// Async global_load_lds double-buffered K/V tiles, 1 barrier per iter.
// LDS unpadded; bank conflicts broken by source-side XOR chunk swizzle.
// S^T = K.Q^T (16x16x32) -> P lands in A-operand layout for PV (16x16x16). O in regs.
// T5: setprio(1) around MFMA clusters (attn +4-7%, m191).
#define BKT 64
__global__ __launch_bounds__(256, 2) void attn(
    const u16* __restrict__ qkv, u16* __restrict__ Oout)
{
  __shared__ __align__(16) u16 Ksh[2][BKT * DD];   // 2 x 16 KB
  __shared__ __align__(16) u16 Vsh[2][DD * BKT];   // 2 x 16 KB

  const int bh = blockIdx.x >> 4, qt = blockIdx.x & 15;
  const int wid = threadIdx.x >> 6, lane = threadIdx.x & 63;
  const int l15 = lane & 15, quad = lane >> 4;
  const int q0 = qt * 128 + wid * 32;
  const u16* qp = qkv + (size_t)bh * LL * DD;
  const u16* kp = qkv + (size_t)BHLD + (size_t)bh * LL * DD;
  const u16* vp = qkv + (size_t)2 * BHLD + (size_t)bh * DD * LL;  // V^T [D][L]

  // Q fragments, held for entire kernel: 2 qfrags x 4 d-frags
  bf16x8 qb[2][4];
#pragma unroll
  for (int qf = 0; qf < 2; qf++)
#pragma unroll
    for (int f = 0; f < 4; f++)
      qb[qf][f] = *(const bf16x8*)&qp[(size_t)(q0 + qf*16 + l15) * DD + f*32 + quad*8];

  float l_acc[2] = {0.f, 0.f};
  f32x4 oacc[2][8] = {};

  // async stage of one K/V tile into buffer `buf` (wave issues 4+4 instrs)
  auto stage = [&](int buf, int k0) {
#pragma unroll
    for (int j = 0; j < 4; j++) {
      const int s = (wid*4 + j)*64 + lane;
      { // K: 64 rows x 16 chunks of 16B
        const int r = s >> 4, c = s & 15;
        const int lc = (c & 8) | ((c & 7) ^ (r & 7));
        gload16(&kp[(size_t)(k0 + r) * DD + lc*8], &Ksh[buf][(wid*4 + j)*512]);
      }
      { // V^T: 128 rows x 8 chunks of 16B
        const int r = s >> 3, c = s & 7;
        const int lc = c ^ (r & 7);
        gload16(&vp[(size_t)r * LL + k0 + lc*8], &Vsh[buf][(wid*4 + j)*512]);
      }
    }
  };

  stage(0, 0);
  int cur = 0;

  for (int k0 = 0; k0 < LL; k0 += BKT) {
    __syncthreads();                       // drains buf[cur] loads; frees buf[cur^1]
    if (k0 + BKT < LL) stage(cur ^ 1, k0 + BKT);

    // S^T = K . Q^T : m = 64 keys (4 tiles), n = 16 q per qfrag
    f32x4 s[2][4] = {};
#pragma unroll
    for (int f = 0; f < 4; f++) {
      bf16x8 kf[4];
#pragma unroll
      for (int mt = 0; mt < 4; mt++) {
        const int rr = mt*16 + l15;
        const int Lc = f*4 + quad;
        const int pc = (Lc & 8) | ((Lc & 7) ^ (rr & 7));
        kf[mt] = *(const bf16x8*)&Ksh[cur][rr*DD + pc*8];
      }
      __builtin_amdgcn_s_setprio(1);
#pragma unroll
      for (int qf = 0; qf < 2; qf++)
#pragma unroll
        for (int mt = 0; mt < 4; mt++)
          s[qf][mt] = __builtin_amdgcn_mfma_f32_16x16x32_bf16(kf[mt], qb[qf][f], s[qf][mt], 0, 0, 0);
      __builtin_amdgcn_s_setprio(0);
    }

    // exp(s - 12), accumulate l, pack P to bf16 A-frags (casts -> v_cvt_pk fusion)
    s16x4 pa[2][4];
#pragma unroll
    for (int qf = 0; qf < 2; qf++) {
#pragma unroll
      for (int mt = 0; mt < 4; mt++) {
        float p0 = __expf(s[qf][mt][0] - 12.f);
        float p1 = __expf(s[qf][mt][1] - 12.f);
        float p2 = __expf(s[qf][mt][2] - 12.f);
        float p3 = __expf(s[qf][mt][3] - 12.f);
        l_acc[qf] += (p0 + p1) + (p2 + p3);
        pa[qf][mt][0] = __builtin_bit_cast(short, (__bf16)p0);
        pa[qf][mt][1] = __builtin_bit_cast(short, (__bf16)p1);
        pa[qf][mt][2] = __builtin_bit_cast(short, (__bf16)p2);
        pa[qf][mt][3] = __builtin_bit_cast(short, (__bf16)p3);
      }
    }

    // O += P . V : per k-chunk t (16 keys), 8 d-tiles, both qfrags share vb
#pragma unroll
    for (int t = 0; t < 4; t++) {
      s16x4 vb[8];
#pragma unroll
      for (int c = 0; c < 8; c++) {
        const int rv = c*16 + l15;
        const int pc = (t*2 + (quad >> 1)) ^ (l15 & 7);
        vb[c] = *(const s16x4*)&Vsh[cur][rv*BKT + pc*8 + (quad & 1)*4];
      }
      __builtin_amdgcn_s_setprio(1);
#pragma unroll
      for (int qf = 0; qf < 2; qf++)
#pragma unroll
        for (int c = 0; c < 8; c++)
          oacc[qf][c] = __builtin_amdgcn_mfma_f32_16x16x16bf16_1k(pa[qf][t], vb[c], oacc[qf][c], 0, 0, 0);
      __builtin_amdgcn_s_setprio(0);
    }
    cur ^= 1;
  }

  // final: reduce l across the 4 quad-replicas, normalize, store
#pragma unroll
  for (int qf = 0; qf < 2; qf++) {
    l_acc[qf] += __shfl_xor(l_acc[qf], 16, 64);
    l_acc[qf] += __shfl_xor(l_acc[qf], 32, 64);
  }
  const int b = bh >> 4, h = bh & 15;
#pragma unroll
  for (int qf = 0; qf < 2; qf++) {
    float lr[4];
#pragma unroll
    for (int r = 0; r < 4; r++)
      lr[r] = 1.0f / __shfl(l_acc[qf], (quad << 4) | (quad*4 + r), 64);
#pragma unroll
    for (int c = 0; c < 8; c++)
#pragma unroll
      for (int r = 0; r < 4; r++) {
        int qrow = q0 + qf*16 + quad*4 + r;
        Oout[((size_t)(b*LL + qrow)) * N2 + h*DD + c*16 + l15] = f2bf(oacc[qf][c][r] * lr[r]);
      }
  }
}

// ---------------- launch ----------------

extern "C" void kernel_launch(void* const* d_in, const int* in_sizes, int n_in,
                              void* d_out, int out_size, void* d_ws, size_t ws_size,
                              hipStream_t stream) {
  const float* x       = (const float*)d_in[0];
  const float* pe      = (const float*)d_in[1];
  const float* qkv_w   = (const float*)d_in[2];
  const float* qkv_b   = (const float*)d_in[3];
  const float* q_scale = (const float*)d_in[4];
  const float* k_scale = (const float*)d_in[5];
  const float* proj_w  = (const float*)d_in[6];
  const float* proj_b  = (const float*)d_in[7];

  // workspace layout (bytes): needs 112 MB
  char* ws = (char*)d_ws;
  u16* xb   = (u16*)(ws + 0);           // [4096][2048] bf16   : 16 MB
  u16* w1t  = (u16*)(ws + 16777216);    // [6144][2048] bf16   : 24 MB
  u16* w2t  = (u16*)(ws + 41943040);    // [2048][2048] bf16   :  8 MB
  u16* qkv  = (u16*)(ws + 50331648);    // q,k [B,H,L,D], v [B,H,D,L] bf16 : 48 MB
  u16* attO = (u16*)(ws + 100663296);   // [4096][2048] bf16   : 16 MB

  f32_to_bf16_vec<<<(MM*KK/4)/256, 256, 0, stream>>>(x, xb, MM*KK/4);
  transpose_f32_bf16<<<dim3(N1/32, KK/32), 256, 0, stream>>>(qkv_w, w1t, KK, N1);
  transpose_f32_bf16<<<dim3(N2/32, KK/32), 256, 0, stream>>>(proj_w, w2t, KK, N2);
  gemm_bt<0><<<dim3(N1/128, MM/128), 256, 0, stream>>>(
      xb, w1t, qkv_b, (void*)qkv, pe, q_scale, k_scale, MM, N1, KK);
  attn<<<BB*HB*(LL/128), 256, 0, stream>>>(qkv, attO);
  gemm_bt<1><<<dim3(N2/128, MM/128), 256, 0, stream>>>(
      attO, w2t, proj_b, d_out, nullptr, nullptr, nullptr, MM, N2, KK);
}